// Round 9
// baseline (1503.940 us; speedup 1.0000x reference)
//
#include <hip/hip_runtime.h>
#include <math.h>

namespace {

constexpr int Hn = 50;    // hidden size
constexpr int Bn = 2048;  // batch
constexpr int Tn = 512;   // sequence length
constexpr int SW = 72;    // plane row stride in shorts (144 B)

constexpr float KS1f = -1.44269504088896340736f;  // -log2(e)   (sigmoid rows i,f,o)
constexpr float KS2f = -2.88539008177792681472f;  // -2*log2(e) (tanh row g, and tanh(c))

typedef short short8 __attribute__((ext_vector_type(8)));
typedef float f32x4 __attribute__((ext_vector_type(4)));

__device__ __forceinline__ unsigned bcu(float f) { return __builtin_bit_cast(unsigned, f); }
__device__ __forceinline__ float bcf(unsigned u) { return __builtin_bit_cast(float, u); }
__device__ __forceinline__ float rcpa(float x) { return __builtin_amdgcn_rcpf(x); }

__device__ __forceinline__ float fexp2(float x) {
#if defined(__has_builtin)
#if __has_builtin(__builtin_amdgcn_exp2f)
  return __builtin_amdgcn_exp2f(x);
#else
  return exp2f(x);
#endif
#else
  return exp2f(x);
#endif
}

__device__ __forceinline__ void wsplit(short* ph, short* pl, float v) {
  const unsigned u = bcu(v);
  *ph = (short)(u >> 16);
  *pl = (short)(bcu(v - bcf(u & 0xFFFF0000u)) >> 16);
}

#define MF(a, b, c) __builtin_amdgcn_mfma_f32_16x16x32_bf16(a, b, c, 0, 0, 0)

// ============================================================================
// FUSED 3-layer LSTM + FC, systolic in time.
// R16: 128 blocks x 512 thr (8 waves = l1:2, l2:3, l3:3) = 2 waves/SIMD,
// cap 256 unified; ALL weights + biases register-resident. ZERO LDS weight
// traffic.
//  - R15 post-mortem: per-CU-iter LDS traffic ~230 ds_read_b128 (s_f4 weight
//    re-reads 80, bias 48, planes 80+) x ~12cy = ~3300cy/iter ~= the measured
//    4360 cy/iter -> the kernel was LDS-PIPE-THROUGHPUT-BOUND. Parking
//    weights in LDS (R11/R15) traded spills for the saturated resource.
//  - R16 distribution: L1 = 2 waves x (7,6) tiles (2 chunks, 16 VGPR/tile);
//    L2/L3 = 3 waves x (5,4,4) tiles (4 chunks, 32 VGPR/tile). Worst path:
//    5x32=160 frag + 20 acc + 20 bias + uh/ul 8 + temps ~= 235 < 256.
//    LDS/iter: ~56 plane b128 reads + ~80 b16 writes ~= ~1000cy (3x cut).
//  - Spill tripwire: WRITE_SIZE (must stay ~8-16 KB). If it jumps: cap
//    overflowed -> move L2/3 bias back to LDS next round.
// Kept: tile-major MFMA triplets (R13: dependent same-acc MFMAs are free);
// exp2-prescaled weights/biases (sigmoid rows * -log2e, tanh rows * -2log2e)
// -> gates rcp(1+exp2(z')); tanh = 2*rcp(1+e)-1; 3-term split-bf16
// (Wh*Uh + Wl*Uh + Wh*Ul); planes K=64: P1=[x,h1(1..50)], P2=[h2], P3=[h3];
// l2 consumes {P1,P2}, l3 {P2,P3}; ONE barrier/iter. Bit-identical math.
// ============================================================================

// frag slots: L1  FI0..13: tile = 7*wl + (FI>>1), chunk = FI&1  (FI>=14 dead)
//             L2/3 FI0..19: j = FI>>2, chunk = FI&3,
//                  tile = (wl==0) ? j : 5+4*(wl-1)+j   (wl>0: j<4)
#define LW(FI)                                                               \
  short8 FH##FI = {0, 0, 0, 0, 0, 0, 0, 0};                                  \
  short8 FL##FI = {0, 0, 0, 0, 0, 0, 0, 0};                                  \
  {                                                                          \
    const int tile_ =                                                        \
        (L == 0)                                                             \
            ? (((FI) < 14) ? (7 * wl + ((FI) >> 1)) : 13)                    \
            : ((wl == 0) ? ((FI) >> 2)                                       \
                         : ((((FI) >> 2) < 4)                                \
                                ? (5 + 4 * (wl - 1) + ((FI) >> 2))           \
                                : 13));                                      \
    const int chunk_ = (L == 0) ? ((FI)&1) : ((FI)&3);                       \
    const int cb_ = 4 * tile_ + (nl >> 2);                                   \
    if (tile_ < 13 && cb_ < Hn) {                                            \
      const int row_ = (nl & 3) * Hn + cb_;                                  \
      const float sc_ = ((nl & 3) == 2) ? KS2f : KS1f;                       \
      _Pragma("unroll") for (int jj = 0; jj < 8; ++jj) {                     \
        const int k_ = 32 * chunk_ + quad * 8 + jj;                          \
        float wv = 0.f;                                                      \
        if (L == 0) {                                                        \
          if (k_ == 0) wv = wihL[row_];                                      \
          else if (k_ <= Hn) wv = whhL[row_ * Hn + k_ - 1];                  \
        } else if (L == 1) {                                                 \
          if (k_ >= 1 && k_ <= Hn) wv = wihL[row_ * Hn + k_ - 1];            \
          else if (k_ >= 64 && k_ < 64 + Hn) wv = whhL[row_ * Hn + k_ - 64]; \
        } else {                                                             \
          if (k_ < Hn) wv = wihL[row_ * Hn + k_];                            \
          else if (k_ >= 64 && k_ < 64 + Hn) wv = whhL[row_ * Hn + k_ - 64]; \
        }                                                                    \
        wv *= sc_;                                                           \
        const unsigned uu = bcu(wv);                                         \
        FH##FI[jj] = (short)(uu >> 16);                                      \
        FL##FI[jj] = (short)(bcu(wv - bcf(uu & 0xFFFF0000u)) >> 16);         \
      }                                                                      \
    }                                                                        \
  }

// bias in REGISTERS, prescaled (rows i,f,o by KS1f; row g by KS2f)
#define BINIT(J)                                                             \
  const int tile##J =                                                        \
      (L == 0) ? (7 * wl + (J))                                              \
               : (((J) < ((wl == 0) ? 5 : 4))                                \
                      ? ((wl == 0) ? (J) : (5 + 4 * (wl - 1) + (J)))         \
                      : 13);                                                 \
  const int tv##J = tile##J < 13;                                            \
  const int cell##J = 4 * tile##J + quad;                                    \
  f32x4 bv##J = {0.f, 0.f, 0.f, 0.f};                                        \
  if (tv##J && cell##J < Hn) {                                               \
    bv##J[0] = biasL[cell##J] * KS1f;                                        \
    bv##J[1] = biasL[Hn + cell##J] * KS1f;                                   \
    bv##J[2] = biasL[2 * Hn + cell##J] * KS2f;                               \
    bv##J[3] = biasL[3 * Hn + cell##J] * KS1f;                               \
  }                                                                          \
  float cs##J = 0.f, hl##J = 0.f;

// tile-major triplet (R13-proven: dependent same-acc MFMAs are free)
#define MTM(J, FI)                                                           \
  if (tv##J) {                                                               \
    ac##J = MF(FH##FI, uh_, ac##J);                                          \
    ac##J = MF(FL##FI, uh_, ac##J);                                          \
    ac##J = MF(FH##FI, ul_, ac##J);                                          \
  }

#define MCH_L1(LC, F0, F1, F2, F3, F4, F5, F6)                               \
  {                                                                          \
    const short8 uh_ = *(const short8*)&p1h[rb][nl][32 * (LC) + quad * 8];   \
    const short8 ul_ = *(const short8*)&p1l[rb][nl][32 * (LC) + quad * 8];   \
    MTM(0, F0) MTM(1, F1) MTM(2, F2) MTM(3, F3) MTM(4, F4) MTM(5, F5)        \
    MTM(6, F6)                                                               \
  }

#define MCH_L23(PH, PL, LC, F0, F1, F2, F3, F4)                              \
  {                                                                          \
    const short8 uh_ = *(const short8*)&PH[rb][nl][32 * (LC) + quad * 8];    \
    const short8 ul_ = *(const short8*)&PL[rb][nl][32 * (LC) + quad * 8];    \
    MTM(0, F0) MTM(1, F1) MTM(2, F2) MTM(3, F3) MTM(4, F4)                   \
  }

// cell update for tile J; SINGLE h write into plane (PH,PL) at k = KO+cell
#define CUP(J, PH, PL, KO)                                                   \
  if (tv##J) {                                                               \
    const float I_ = rcpa(1.0f + fexp2(ac##J[0]));                           \
    const float F_ = rcpa(1.0f + fexp2(ac##J[1]));                           \
    const float G_ = fmaf(2.0f, rcpa(1.0f + fexp2(ac##J[2])), -1.0f);        \
    const float O_ = rcpa(1.0f + fexp2(ac##J[3]));                           \
    cs##J = fmaf(F_, cs##J, I_ * G_);                                        \
    const float tc_ = fmaf(2.0f, rcpa(1.0f + fexp2(cs##J * KS2f)), -1.0f);   \
    const float hv = O_ * tc_;                                               \
    hl##J = hv;                                                              \
    if (cell##J < Hn)                                                        \
      wsplit(&PH[wb][nl][(KO) + cell##J], &PL[wb][nl][(KO) + cell##J], hv);  \
  }

__global__ __launch_bounds__(512, 1) void lstm_fused(
    const float* __restrict__ xg,    // [B][T]
    const float* __restrict__ wih1, const float* __restrict__ whh1,
    const float* __restrict__ b1, const float* __restrict__ wih2,
    const float* __restrict__ whh2, const float* __restrict__ b2,
    const float* __restrict__ wih3, const float* __restrict__ whh3,
    const float* __restrict__ b3, const float* __restrict__ wfc,
    const float* __restrict__ bfc, float* __restrict__ out)  // [B]
{
  __shared__ __align__(16) short p1h[2][16][SW];  // [x | h1(1..50)]
  __shared__ __align__(16) short p1l[2][16][SW];
  __shared__ __align__(16) short p2h[2][16][SW];  // [h2(0..49)]
  __shared__ __align__(16) short p2l[2][16][SW];
  __shared__ __align__(16) short p3h[2][16][SW];  // [h3(0..49)]
  __shared__ __align__(16) short p3l[2][16][SW];
  __shared__ float s_fc[3][16];

  const int tid = threadIdx.x;
  const int w = tid >> 6;
  const int lane = tid & 63;
  const int quad = lane >> 4;
  const int nl = lane & 15;
  const int L = (w < 2) ? 0 : (w < 5) ? 1 : 2;
  const int wl = w - (L == 0 ? 0 : (L == 1 ? 2 : 5));
  const int eb = blockIdx.x * 16;

  const float* wihL = (L == 0) ? wih1 : (L == 1) ? wih2 : wih3;
  const float* whhL = (L == 0) ? whh1 : (L == 1) ? whh2 : whh3;
  const float* biasL = (L == 0) ? b1 : (L == 1) ? b2 : b3;

  LW(0) LW(1) LW(2) LW(3) LW(4) LW(5) LW(6) LW(7) LW(8) LW(9)
  LW(10) LW(11) LW(12) LW(13) LW(14) LW(15) LW(16) LW(17) LW(18) LW(19)

  BINIT(0) BINIT(1) BINIT(2) BINIT(3) BINIT(4) BINIT(5) BINIT(6)

  for (int i = tid; i < 2 * 16 * SW; i += 512) {
    (&p1h[0][0][0])[i] = 0;
    (&p1l[0][0][0])[i] = 0;
    (&p2h[0][0][0])[i] = 0;
    (&p2l[0][0][0])[i] = 0;
    (&p3h[0][0][0])[i] = 0;
    (&p3l[0][0][0])[i] = 0;
  }
  __syncthreads();
  if (w == 0 && lane < 16) {
    const float xv = xg[(size_t)(eb + lane) * Tn + 0];
    wsplit(&p1h[0][lane][0], &p1l[0][lane][0], xv);
  }
  __syncthreads();

#pragma unroll 1
  for (int i = 0; i < Tn + 2; ++i) {
    const int rb = i & 1, wb = rb ^ 1;
    if (L == 0) {
      if (i < Tn) {
        float xv = 0.f;
        if (w == 0 && lane < 16 && i + 1 < Tn)
          xv = xg[(size_t)(eb + lane) * Tn + (i + 1)];
        f32x4 ac0 = bv0, ac1 = bv1, ac2 = bv2, ac3 = bv3, ac4 = bv4,
              ac5 = bv5, ac6 = bv6;
        MCH_L1(0, 0, 2, 4, 6, 8, 10, 12)
        MCH_L1(1, 1, 3, 5, 7, 9, 11, 13)
        CUP(0, p1h, p1l, 1)
        CUP(1, p1h, p1l, 1)
        CUP(2, p1h, p1l, 1)
        CUP(3, p1h, p1l, 1)
        CUP(4, p1h, p1l, 1)
        CUP(5, p1h, p1l, 1)
        CUP(6, p1h, p1l, 1)
        if (w == 0 && lane < 16)
          wsplit(&p1h[wb][lane][0], &p1l[wb][lane][0], xv);
      }
    } else if (L == 1) {
      if (i >= 1 && i <= Tn) {
        f32x4 ac0 = bv0, ac1 = bv1, ac2 = bv2, ac3 = bv3, ac4 = bv4;
        MCH_L23(p1h, p1l, 0, 0, 4, 8, 12, 16)   // combined k 0..31  (h1)
        MCH_L23(p1h, p1l, 1, 1, 5, 9, 13, 17)   // combined k 32..63 (h1)
        MCH_L23(p2h, p2l, 0, 2, 6, 10, 14, 18)  // combined k 64..95 (h2)
        MCH_L23(p2h, p2l, 1, 3, 7, 11, 15, 19)  // combined k 96..127(h2)
        CUP(0, p2h, p2l, 0)
        CUP(1, p2h, p2l, 0)
        CUP(2, p2h, p2l, 0)
        CUP(3, p2h, p2l, 0)
        CUP(4, p2h, p2l, 0)
      }
    } else {
      if (i >= 2) {
        f32x4 ac0 = bv0, ac1 = bv1, ac2 = bv2, ac3 = bv3, ac4 = bv4;
        MCH_L23(p2h, p2l, 0, 0, 4, 8, 12, 16)   // h2
        MCH_L23(p2h, p2l, 1, 1, 5, 9, 13, 17)
        MCH_L23(p3h, p3l, 0, 2, 6, 10, 14, 18)  // h3
        MCH_L23(p3h, p3l, 1, 3, 7, 11, 15, 19)
        CUP(0, p3h, p3l, 0)
        CUP(1, p3h, p3l, 0)
        CUP(2, p3h, p3l, 0)
        CUP(3, p3h, p3l, 0)
        CUP(4, p3h, p3l, 0)
      }
    }
    __syncthreads();
  }

  if (L == 2) {
    float pfc = 0.f;
    if (tv0 && cell0 < Hn) pfc += hl0 * wfc[cell0];
    if (tv1 && cell1 < Hn) pfc += hl1 * wfc[cell1];
    if (tv2 && cell2 < Hn) pfc += hl2 * wfc[cell2];
    if (tv3 && cell3 < Hn) pfc += hl3 * wfc[cell3];
    if (tv4 && cell4 < Hn) pfc += hl4 * wfc[cell4];
    pfc += __shfl_xor(pfc, 16);  // sum over quads (cells)
    pfc += __shfl_xor(pfc, 32);
    if (lane < 16) s_fc[wl][lane] = pfc;
  }
  __syncthreads();
  if (tid < 16)
    out[eb + tid] = bfc[0] + s_fc[0][tid] + s_fc[1][tid] + s_fc[2][tid];
}

}  // namespace

extern "C" void kernel_launch(void* const* d_in, const int* in_sizes, int n_in,
                              void* d_out, int out_size, void* d_ws, size_t ws_size,
                              hipStream_t stream) {
  const float* x    = (const float*)d_in[0];
  const float* wih1 = (const float*)d_in[1];
  const float* whh1 = (const float*)d_in[2];
  const float* b1   = (const float*)d_in[3];
  const float* wih2 = (const float*)d_in[4];
  const float* whh2 = (const float*)d_in[5];
  const float* b2   = (const float*)d_in[6];
  const float* wih3 = (const float*)d_in[7];
  const float* whh3 = (const float*)d_in[8];
  const float* b3   = (const float*)d_in[9];
  const float* wfc  = (const float*)d_in[10];
  const float* bfc  = (const float*)d_in[11];
  float* out = (float*)d_out;

  lstm_fused<<<dim3(Bn / 16), dim3(512), 0, stream>>>(
      x, wih1, whh1, b1, wih2, whh2, b2, wih3, whh3, b3, wfc, bfc, out);
}

// Round 12
// 1070.875 us; speedup vs baseline: 1.4044x; 1.4044x over previous
//
#include <hip/hip_runtime.h>
#include <math.h>

namespace {

constexpr int Hn = 50;    // hidden size
constexpr int Bn = 2048;  // batch
constexpr int Tn = 512;   // sequence length
constexpr int SW = 72;    // plane row stride in shorts (144 B)

constexpr float KS1f = -1.44269504088896340736f;  // -log2(e)   (sigmoid rows i,f,o)
constexpr float KS2f = -2.88539008177792681472f;  // -2*log2(e) (tanh row g, and tanh(c))

typedef short short8 __attribute__((ext_vector_type(8)));
typedef float f32x4 __attribute__((ext_vector_type(4)));

__device__ __forceinline__ unsigned bcu(float f) { return __builtin_bit_cast(unsigned, f); }
__device__ __forceinline__ float bcf(unsigned u) { return __builtin_bit_cast(float, u); }
__device__ __forceinline__ float rcpa(float x) { return __builtin_amdgcn_rcpf(x); }

__device__ __forceinline__ float fexp2(float x) {
#if defined(__has_builtin)
#if __has_builtin(__builtin_amdgcn_exp2f)
  return __builtin_amdgcn_exp2f(x);
#else
  return exp2f(x);
#endif
#else
  return exp2f(x);
#endif
}

__device__ __forceinline__ void wsplit(short* ph, short* pl, float v) {
  const unsigned u = bcu(v);
  *ph = (short)(u >> 16);
  *pl = (short)(bcu(v - bcf(u & 0xFFFF0000u)) >> 16);
}

#define MF(a, b, c) __builtin_amdgcn_mfma_f32_16x16x32_bf16(a, b, c, 0, 0, 0)

// ============================================================================
// FUSED 3-layer LSTM + FC, systolic in time. SINGLE-BLOCK-PER-GROUP (the
// R17/R18 cross-block pipeline hung twice with zero diagnostics; abandoned).
// R19: 128 blocks x 768 thr (12 waves, 3/SIMD, cap 170) -- rebalanced so
// almost ALL weights are register-resident, attacking the CU-shared LDS pipe
// (R15 audit: ~208 b128 reads/iter ~= 2500-3100cy of the 4360cy iter; 80 of
// those were s_f4 weight re-reads, 48 bias).
//  - Fragment liveness is the UNION over wave-roles (R16 lesson): max pairs,
//    not sum. New split: L1: 3 waves (5,4,4 tiles, 2 chunks); L2: 4 waves
//    (4,3,3,3; the 4th tile of wl0 is the ONLY LDS-parked tile, s_fx 8KB);
//    L3: 5 waves (3,3,3,2,2). Union = 12 pairs = 96 VGPR; total ~155 < 170.
//    Weight re-reads: 80 -> 8 per iter. Bias stays in LDS (keeps margin).
//  - Spill tripwire: WRITE_SIZE (~8 KB). If it jumps: drop L1-w0 to 4 tiles.
// Kept: tile-major MFMA triplets (R13: dependent same-acc MFMAs are free);
// exp2-prescaled weights/biases -> gates rcp(1+exp2(z')), tanh=2*rcp(1+e)-1;
// 3-term split-bf16 (Wh*Uh + Wl*Uh + Wh*Ul); planes K=64: P1=[x,h1(1..50)],
// P2=[h2], P3=[h3]; l2 consumes {P1,P2}, l3 {P2,P3}; ONE barrier/iter.
// Bit-identical math to R15 (same per-acc accumulation order).
// ============================================================================

// reg slots: L1: FI0..9:  tile = t(FI>>1), chunk = FI&1
//            L2/3: FI0..11: tile = t(FI>>2), chunk = FI&3
// LDS slots: FI16..19 (L2-wl0 only): tile = t3s (=3), chunk = FI&3
#define TSEL(J_) ((J_) == 0 ? t0s : (J_) == 1 ? t1s : (J_) == 2 ? t2s       \
                  : (J_) == 3 ? t3s : t4s)

#define LW(FI)                                                               \
  short8 FH##FI = {0, 0, 0, 0, 0, 0, 0, 0};                                  \
  short8 FL##FI = {0, 0, 0, 0, 0, 0, 0, 0};                                  \
  {                                                                          \
    const int tile_ =                                                        \
        ((FI) >= 16) ? ((L == 1 && wl == 0) ? t3s : 13)                      \
        : (L == 0)   ? (((FI) < 10) ? TSEL((FI) >> 1) : 13)                  \
                     : TSEL((FI) >> 2);                                      \
    const int chunk_ = ((FI) >= 16) ? ((FI)&3)                               \
                       : (L == 0)   ? ((FI)&1)                               \
                                    : ((FI)&3);                              \
    const int cb_ = 4 * tile_ + (nl >> 2);                                   \
    if (tile_ < 13 && cb_ < Hn) {                                            \
      const int row_ = (nl & 3) * Hn + cb_;                                  \
      const float sc_ = ((nl & 3) == 2) ? KS2f : KS1f;                       \
      _Pragma("unroll") for (int jj = 0; jj < 8; ++jj) {                     \
        const int k_ = 32 * chunk_ + quad * 8 + jj;                          \
        float wv = 0.f;                                                      \
        if (L == 0) {                                                        \
          if (k_ == 0) wv = wihL[row_];                                      \
          else if (k_ <= Hn) wv = whhL[row_ * Hn + k_ - 1];                  \
        } else if (L == 1) {                                                 \
          if (k_ >= 1 && k_ <= Hn) wv = wihL[row_ * Hn + k_ - 1];            \
          else if (k_ >= 64 && k_ < 64 + Hn) wv = whhL[row_ * Hn + k_ - 64]; \
        } else {                                                             \
          if (k_ < Hn) wv = wihL[row_ * Hn + k_];                            \
          else if (k_ >= 64 && k_ < 64 + Hn) wv = whhL[row_ * Hn + k_ - 64]; \
        }                                                                    \
        wv *= sc_;                                                           \
        const unsigned uu = bcu(wv);                                         \
        FH##FI[jj] = (short)(uu >> 16);                                      \
        FL##FI[jj] = (short)(bcu(wv - bcf(uu & 0xFFFF0000u)) >> 16);         \
      }                                                                      \
    }                                                                        \
  }

#define BINIT(J)                                                             \
  const int tile##J = TSEL(J);                                               \
  const int tv##J = tile##J < 13;                                            \
  const int cell##J = 4 * tile##J + quad;                                    \
  float cs##J = 0.f, hl##J = 0.f;

// one-time prologue store of pre-scaled bias into LDS (nl==0 lanes only)
#define STB(J)                                                               \
  if (tv##J) {                                                               \
    float b0_ = 0.f, b1_ = 0.f, b2_ = 0.f, b3_ = 0.f;                        \
    if (cell##J < Hn) {                                                      \
      b0_ = biasL[cell##J] * KS1f;                                           \
      b1_ = biasL[Hn + cell##J] * KS1f;                                      \
      b2_ = biasL[2 * Hn + cell##J] * KS2f;                                  \
      b3_ = biasL[3 * Hn + cell##J] * KS1f;                                  \
    }                                                                        \
    s_bv[w][J][quad][0] = b0_;                                               \
    s_bv[w][J][quad][1] = b1_;                                               \
    s_bv[w][J][quad][2] = b2_;                                               \
    s_bv[w][J][quad][3] = b3_;                                               \
  }

// tile-major triplet (R13-proven: dependent same-acc MFMAs are free)
#define MTM(J, FI)                                                           \
  if (tv##J) {                                                               \
    ac##J = MF(FH##FI, uh_, ac##J);                                          \
    ac##J = MF(FL##FI, uh_, ac##J);                                          \
    ac##J = MF(FH##FI, ul_, ac##J);                                          \
  }

// L2-wl0's 4th tile (J=3) from LDS
#define MTMS3(CI)                                                            \
  if (tv3) {                                                                 \
    const short8 fh_ = s_fx[CI][0][lane];                                    \
    const short8 fl_ = s_fx[CI][1][lane];                                    \
    ac3 = MF(fh_, uh_, ac3);                                                 \
    ac3 = MF(fl_, uh_, ac3);                                                 \
    ac3 = MF(fh_, ul_, ac3);                                                 \
  }

#define MCH_L1(LC, F0, F1, F2, F3, F4)                                       \
  {                                                                          \
    const short8 uh_ = *(const short8*)&p1h[rb][nl][32 * (LC) + quad * 8];   \
    const short8 ul_ = *(const short8*)&p1l[rb][nl][32 * (LC) + quad * 8];   \
    MTM(0, F0) MTM(1, F1) MTM(2, F2) MTM(3, F3) MTM(4, F4)                   \
  }

#define MCH_L2(PH, PL, LC, CI, F0, F1, F2)                                   \
  {                                                                          \
    const short8 uh_ = *(const short8*)&PH[rb][nl][32 * (LC) + quad * 8];    \
    const short8 ul_ = *(const short8*)&PL[rb][nl][32 * (LC) + quad * 8];    \
    MTM(0, F0) MTM(1, F1) MTM(2, F2) MTMS3(CI)                               \
  }

#define MCH_L3(PH, PL, LC, F0, F1, F2)                                       \
  {                                                                          \
    const short8 uh_ = *(const short8*)&PH[rb][nl][32 * (LC) + quad * 8];    \
    const short8 ul_ = *(const short8*)&PL[rb][nl][32 * (LC) + quad * 8];    \
    MTM(0, F0) MTM(1, F1) MTM(2, F2)                                         \
  }

// cell update for tile J; SINGLE h write into plane (PH,PL) at k = KO+cell
#define CUP(J, PH, PL, KO)                                                   \
  if (tv##J) {                                                               \
    const float I_ = rcpa(1.0f + fexp2(ac##J[0]));                           \
    const float F_ = rcpa(1.0f + fexp2(ac##J[1]));                           \
    const float G_ = fmaf(2.0f, rcpa(1.0f + fexp2(ac##J[2])), -1.0f);        \
    const float O_ = rcpa(1.0f + fexp2(ac##J[3]));                           \
    cs##J = fmaf(F_, cs##J, I_ * G_);                                        \
    const float tc_ = fmaf(2.0f, rcpa(1.0f + fexp2(cs##J * KS2f)), -1.0f);   \
    const float hv = O_ * tc_;                                               \
    hl##J = hv;                                                              \
    if (cell##J < Hn)                                                        \
      wsplit(&PH[wb][nl][(KO) + cell##J], &PL[wb][nl][(KO) + cell##J], hv);  \
  }

__global__ __launch_bounds__(768, 3) void lstm_fused(
    const float* __restrict__ xg,    // [B][T]
    const float* __restrict__ wih1, const float* __restrict__ whh1,
    const float* __restrict__ b1, const float* __restrict__ wih2,
    const float* __restrict__ whh2, const float* __restrict__ b2,
    const float* __restrict__ wih3, const float* __restrict__ whh3,
    const float* __restrict__ b3, const float* __restrict__ wfc,
    const float* __restrict__ bfc, float* __restrict__ out)  // [B]
{
  __shared__ __align__(16) short p1h[2][16][SW];  // [x | h1(1..50)]
  __shared__ __align__(16) short p1l[2][16][SW];
  __shared__ __align__(16) short p2h[2][16][SW];  // [h2(0..49)]
  __shared__ __align__(16) short p2l[2][16][SW];
  __shared__ __align__(16) short p3h[2][16][SW];  // [h3(0..49)]
  __shared__ __align__(16) short p3l[2][16][SW];
  __shared__ __align__(16) float s_bv[12][5][4][4];  // pre-scaled bias
  __shared__ __align__(16) short8 s_fx[4][2][64];    // L2 tile-3 frags (8 KB)
  __shared__ float s_fc[5][16];

  const int tid = threadIdx.x;
  const int w = tid >> 6;
  const int lane = tid & 63;
  const int quad = lane >> 4;
  const int nl = lane & 15;
  const int eb = blockIdx.x * 16;

  // wave -> (layer, tile set). L1: w0-2 (5,4,4); L2: w3-6 (3+1LDS,3,3,3);
  // L3: w7-11 (3,3,3,2,2).
  int L, wl;
  if (w < 3) { L = 0; wl = w; }
  else if (w < 7) { L = 1; wl = w - 3; }
  else { L = 2; wl = w - 7; }

  int t0s = 13, t1s = 13, t2s = 13, t3s = 13, t4s = 13;
  if (L == 0) {
    if (wl == 0) { t0s = 0; t1s = 1; t2s = 2; t3s = 3; t4s = 4; }
    else if (wl == 1) { t0s = 5; t1s = 6; t2s = 7; t3s = 8; }
    else { t0s = 9; t1s = 10; t2s = 11; t3s = 12; }
  } else if (L == 1) {
    if (wl == 0) { t0s = 0; t1s = 1; t2s = 2; t3s = 3; }  // t3 via LDS
    else { t0s = 3 * wl + 1; t1s = t0s + 1; t2s = t0s + 2; }
  } else {
    if (wl < 3) { t0s = 3 * wl; t1s = t0s + 1; t2s = t0s + 2; }
    else if (wl == 3) { t0s = 9; t1s = 10; }
    else { t0s = 11; t1s = 12; }
  }

  const float* wihL = (L == 0) ? wih1 : (L == 1) ? wih2 : wih3;
  const float* whhL = (L == 0) ? whh1 : (L == 1) ? whh2 : whh3;
  const float* biasL = (L == 0) ? b1 : (L == 1) ? b2 : b3;

  LW(0) LW(1) LW(2) LW(3) LW(4) LW(5) LW(6) LW(7) LW(8) LW(9)
  LW(10) LW(11)
  LW(16) LW(17) LW(18) LW(19)

  // park L2-wl0's 4th tile in LDS; those registers die here
  if (L == 1 && wl == 0) {
    s_fx[0][0][lane] = FH16; s_fx[0][1][lane] = FL16;
    s_fx[1][0][lane] = FH17; s_fx[1][1][lane] = FL17;
    s_fx[2][0][lane] = FH18; s_fx[2][1][lane] = FL18;
    s_fx[3][0][lane] = FH19; s_fx[3][1][lane] = FL19;
  }

  BINIT(0) BINIT(1) BINIT(2) BINIT(3) BINIT(4)

  for (int i = tid; i < 2 * 16 * SW; i += 768) {
    (&p1h[0][0][0])[i] = 0;
    (&p1l[0][0][0])[i] = 0;
    (&p2h[0][0][0])[i] = 0;
    (&p2l[0][0][0])[i] = 0;
    (&p3h[0][0][0])[i] = 0;
    (&p3l[0][0][0])[i] = 0;
  }
  for (int i = tid; i < 12 * 5 * 4 * 4; i += 768) (&s_bv[0][0][0][0])[i] = 0.f;
  __syncthreads();
  if (w == 0 && lane < 16) {
    const float xv = xg[(size_t)(eb + lane) * Tn + 0];
    wsplit(&p1h[0][lane][0], &p1l[0][lane][0], xv);
  }
  if (nl == 0) {
    STB(0) STB(1) STB(2) STB(3) STB(4)
  }
  __syncthreads();

#pragma unroll 1
  for (int i = 0; i < Tn + 2; ++i) {
    const int rb = i & 1, wb = rb ^ 1;
    if (L == 0) {
      if (i < Tn) {
        float xv = 0.f;
        if (w == 0 && lane < 16 && i + 1 < Tn)
          xv = xg[(size_t)(eb + lane) * Tn + (i + 1)];
        f32x4 ac0 = *(const f32x4*)s_bv[w][0][quad];
        f32x4 ac1 = *(const f32x4*)s_bv[w][1][quad];
        f32x4 ac2 = *(const f32x4*)s_bv[w][2][quad];
        f32x4 ac3 = *(const f32x4*)s_bv[w][3][quad];
        f32x4 ac4 = *(const f32x4*)s_bv[w][4][quad];
        MCH_L1(0, 0, 2, 4, 6, 8)
        MCH_L1(1, 1, 3, 5, 7, 9)
        CUP(0, p1h, p1l, 1)
        CUP(1, p1h, p1l, 1)
        CUP(2, p1h, p1l, 1)
        CUP(3, p1h, p1l, 1)
        CUP(4, p1h, p1l, 1)
        if (w == 0 && lane < 16)
          wsplit(&p1h[wb][lane][0], &p1l[wb][lane][0], xv);
      }
    } else if (L == 1) {
      if (i >= 1 && i <= Tn) {
        f32x4 ac0 = *(const f32x4*)s_bv[w][0][quad];
        f32x4 ac1 = *(const f32x4*)s_bv[w][1][quad];
        f32x4 ac2 = *(const f32x4*)s_bv[w][2][quad];
        f32x4 ac3 = *(const f32x4*)s_bv[w][3][quad];
        MCH_L2(p1h, p1l, 0, 0, 0, 4, 8)    // combined k 0..31  (h1)
        MCH_L2(p1h, p1l, 1, 1, 1, 5, 9)    // combined k 32..63 (h1)
        MCH_L2(p2h, p2l, 0, 2, 2, 6, 10)   // combined k 64..95 (h2)
        MCH_L2(p2h, p2l, 1, 3, 3, 7, 11)   // combined k 96..127(h2)
        CUP(0, p2h, p2l, 0)
        CUP(1, p2h, p2l, 0)
        CUP(2, p2h, p2l, 0)
        CUP(3, p2h, p2l, 0)
      }
    } else {
      if (i >= 2) {
        f32x4 ac0 = *(const f32x4*)s_bv[w][0][quad];
        f32x4 ac1 = *(const f32x4*)s_bv[w][1][quad];
        f32x4 ac2 = *(const f32x4*)s_bv[w][2][quad];
        MCH_L3(p2h, p2l, 0, 0, 4, 8)    // h2
        MCH_L3(p2h, p2l, 1, 1, 5, 9)
        MCH_L3(p3h, p3l, 0, 2, 6, 10)   // h3
        MCH_L3(p3h, p3l, 1, 3, 7, 11)
        CUP(0, p3h, p3l, 0)
        CUP(1, p3h, p3l, 0)
        CUP(2, p3h, p3l, 0)
      }
    }
    __syncthreads();
  }

  if (L == 2) {
    float pfc = 0.f;
    if (tv0 && cell0 < Hn) pfc += hl0 * wfc[cell0];
    if (tv1 && cell1 < Hn) pfc += hl1 * wfc[cell1];
    if (tv2 && cell2 < Hn) pfc += hl2 * wfc[cell2];
    pfc += __shfl_xor(pfc, 16);  // sum over quads (cells)
    pfc += __shfl_xor(pfc, 32);
    if (lane < 16) s_fc[wl][lane] = pfc;
  }
  __syncthreads();
  if (tid < 16)
    out[eb + tid] = bfc[0] + s_fc[0][tid] + s_fc[1][tid] + s_fc[2][tid] +
                    s_fc[3][tid] + s_fc[4][tid];
}

}  // namespace

extern "C" void kernel_launch(void* const* d_in, const int* in_sizes, int n_in,
                              void* d_out, int out_size, void* d_ws, size_t ws_size,
                              hipStream_t stream) {
  const float* x    = (const float*)d_in[0];
  const float* wih1 = (const float*)d_in[1];
  const float* whh1 = (const float*)d_in[2];
  const float* b1   = (const float*)d_in[3];
  const float* wih2 = (const float*)d_in[4];
  const float* whh2 = (const float*)d_in[5];
  const float* b2   = (const float*)d_in[6];
  const float* wih3 = (const float*)d_in[7];
  const float* whh3 = (const float*)d_in[8];
  const float* b3   = (const float*)d_in[9];
  const float* wfc  = (const float*)d_in[10];
  const float* bfc  = (const float*)d_in[11];
  float* out = (float*)d_out;

  lstm_fused<<<dim3(Bn / 16), dim3(768), 0, stream>>>(
      x, wih1, whh1, b1, wih2, whh2, b2, wih3, whh3, b3, wfc, bfc, out);
}

// Round 13
// 933.466 us; speedup vs baseline: 1.6111x; 1.1472x over previous
//
#include <hip/hip_runtime.h>
#include <math.h>

namespace {

constexpr int Hn = 50;    // hidden size
constexpr int Bn = 2048;  // batch
constexpr int Tn = 512;   // sequence length
constexpr int SW = 72;    // plane row stride in shorts (144 B)

constexpr float KS1f = -1.44269504088896340736f;  // -log2(e)   (sigmoid rows i,f,o)
constexpr float KS2f = -2.88539008177792681472f;  // -2*log2(e) (tanh row g, and tanh(c))

typedef short short8 __attribute__((ext_vector_type(8)));
typedef float f32x4 __attribute__((ext_vector_type(4)));

__device__ __forceinline__ unsigned bcu(float f) { return __builtin_bit_cast(unsigned, f); }
__device__ __forceinline__ float bcf(unsigned u) { return __builtin_bit_cast(float, u); }
__device__ __forceinline__ float rcpa(float x) { return __builtin_amdgcn_rcpf(x); }

__device__ __forceinline__ float fexp2(float x) {
#if defined(__has_builtin)
#if __has_builtin(__builtin_amdgcn_exp2f)
  return __builtin_amdgcn_exp2f(x);
#else
  return exp2f(x);
#endif
#else
  return exp2f(x);
#endif
}

__device__ __forceinline__ void wsplit(short* ph, short* pl, float v) {
  const unsigned u = bcu(v);
  *ph = (short)(u >> 16);
  *pl = (short)(bcu(v - bcf(u & 0xFFFF0000u)) >> 16);
}

#define MF(a, b, c) __builtin_amdgcn_mfma_f32_16x16x32_bf16(a, b, c, 0, 0, 0)

// ============================================================================
// FUSED 3-layer LSTM + FC, systolic in time. R20 = R15 (934us, zero-spill)
// + T5 s_setprio around MFMA clusters.
//  - Allocator model CONFIRMED across R10/12/14/16/19: with MFMA accs live,
//    the compiler splits the unified file cap/2 arch + cap/2 AGPR. Arch
//    budget at (768,3) = 85; R19's 96-VGPR fragment union spilled (WRITE
//    7304KB). R15 (64-VGPR union) is the feasible optimum of this split.
//  - Residual iter budget (4360cy): ~390 trans ops (exp2/rcp, 1/4-rate)
//    ~1500cy/SIMD + 470cy MFMA + VALU; barrier-locked phases jam the trans
//    pipe while MFMA idles and vice versa. Each SIMD hosts {L1,L2,L3} waves
//    (w%4 round-robin) = role-diverse -> T5 applies: setprio(1) during MFMA
//    cluster lets MFMA-phase waves preempt trans-phase waves.
// R15 (kept): 128 blk x 768 thr (12 waves: L1 4 (4,4,4,1 tiles x2 chunks),
// L2 4 / L3 4 (tiles wl+4J, J<2 reg; J2 tiles 8..11 + J3 tile 12 in LDS
// s_f4j2/s_f4j3, re-read per chunk)); biases in LDS (s_bv); tile-major MFMA
// triplets (R13: dependent same-acc MFMAs free); exp2-prescaled weights ->
// gates rcp(1+exp2(z')), tanh=2*rcp(1+e)-1; 3-term split-bf16; planes K=64:
// P1=[x,h1(1..50)], P2=[h2], P3=[h3]; ONE barrier/iter. Bit-identical math.
// ============================================================================

#define LW(FI)                                                               \
  short8 FH##FI = {0, 0, 0, 0, 0, 0, 0, 0};                                  \
  short8 FL##FI = {0, 0, 0, 0, 0, 0, 0, 0};                                  \
  {                                                                          \
    const int tile_ =                                                        \
        ((FI) >= 16) ? ((L == 0 || wl != 0) ? 13 : 12)                       \
        : ((FI) >= 8) ? ((L == 0) ? 13 : (wl + 8))                           \
        : (L == 0)    ? (wl + 4 * ((FI) >> 1))                               \
                      : (wl + 4 * ((FI) >> 2));                              \
    const int chunk_ = ((FI) >= 8) ? ((FI)&3)                                \
                       : (L == 0)  ? ((FI)&1)                                \
                                   : ((FI)&3);                               \
    const int cb_ = 4 * tile_ + (nl >> 2);                                   \
    if (tile_ < 13 && cb_ < Hn) {                                            \
      const int row_ = (nl & 3) * Hn + cb_;                                  \
      const float sc_ = ((nl & 3) == 2) ? KS2f : KS1f;                       \
      _Pragma("unroll") for (int jj = 0; jj < 8; ++jj) {                     \
        const int k_ = 32 * chunk_ + quad * 8 + jj;                          \
        float wv = 0.f;                                                      \
        if (L == 0) {                                                        \
          if (k_ == 0) wv = wihL[row_];                                      \
          else if (k_ <= Hn) wv = whhL[row_ * Hn + k_ - 1];                  \
        } else if (L == 1) {                                                 \
          if (k_ >= 1 && k_ <= Hn) wv = wihL[row_ * Hn + k_ - 1];            \
          else if (k_ >= 64 && k_ < 64 + Hn) wv = whhL[row_ * Hn + k_ - 64]; \
        } else {                                                             \
          if (k_ < Hn) wv = wihL[row_ * Hn + k_];                            \
          else if (k_ >= 64 && k_ < 64 + Hn) wv = whhL[row_ * Hn + k_ - 64]; \
        }                                                                    \
        wv *= sc_;                                                           \
        const unsigned uu = bcu(wv);                                         \
        FH##FI[jj] = (short)(uu >> 16);                                      \
        FL##FI[jj] = (short)(bcu(wv - bcf(uu & 0xFFFF0000u)) >> 16);         \
      }                                                                      \
    }                                                                        \
  }

#define BINIT(J)                                                             \
  const int tile##J = wl + 4 * (J);                                          \
  const int tv##J = tile##J < 13;                                            \
  const int cell##J = 4 * tile##J + quad;                                    \
  float cs##J = 0.f, hl##J = 0.f;

// one-time prologue store of pre-scaled bias into LDS (nl==0 lanes only)
#define STB(J)                                                               \
  if (tv##J) {                                                               \
    float b0_ = 0.f, b1_ = 0.f, b2_ = 0.f, b3_ = 0.f;                        \
    if (cell##J < Hn) {                                                      \
      b0_ = biasL[cell##J] * KS1f;                                           \
      b1_ = biasL[Hn + cell##J] * KS1f;                                      \
      b2_ = biasL[2 * Hn + cell##J] * KS2f;                                  \
      b3_ = biasL[3 * Hn + cell##J] * KS1f;                                  \
    }                                                                        \
    s_bv[w][J][quad][0] = b0_;                                               \
    s_bv[w][J][quad][1] = b1_;                                               \
    s_bv[w][J][quad][2] = b2_;                                               \
    s_bv[w][J][quad][3] = b3_;                                               \
  }

// tile-major triplet (R13-proven: dependent same-acc MFMAs are free)
#define MTM(J, FI)                                                           \
  if (tv##J) {                                                               \
    ac##J = MF(FH##FI, uh_, ac##J);                                          \
    ac##J = MF(FL##FI, uh_, ac##J);                                          \
    ac##J = MF(FH##FI, ul_, ac##J);                                          \
  }

// J2 (tiles 8..11, all L2/3 waves) from LDS
#define MTMS2(CI)                                                            \
  {                                                                          \
    const short8 fh_ = s_f4j2[wz2][wl][CI][0][lane];                         \
    const short8 fl_ = s_f4j2[wz2][wl][CI][1][lane];                         \
    ac2 = MF(fh_, uh_, ac2);                                                 \
    ac2 = MF(fl_, uh_, ac2);                                                 \
    ac2 = MF(fh_, ul_, ac2);                                                 \
  }

// J3 (tile 12, wl==0 waves of L2/3) from LDS
#define MTMS3(CI)                                                            \
  if (tv3) {                                                                 \
    const short8 fh_ = s_f4j3[wz2][CI][0][lane];                             \
    const short8 fl_ = s_f4j3[wz2][CI][1][lane];                             \
    ac3 = MF(fh_, uh_, ac3);                                                 \
    ac3 = MF(fl_, uh_, ac3);                                                 \
    ac3 = MF(fh_, ul_, ac3);                                                 \
  }

#define MCH_L1(LC, F0, F1, F2, F3)                                           \
  {                                                                          \
    const short8 uh_ = *(const short8*)&p1h[rb][nl][32 * (LC) + quad * 8];   \
    const short8 ul_ = *(const short8*)&p1l[rb][nl][32 * (LC) + quad * 8];   \
    MTM(0, F0) MTM(1, F1) MTM(2, F2) MTM(3, F3)                              \
  }

#define MCH_L23(PH, PL, LC, CI, F0, F1)                                      \
  {                                                                          \
    const short8 uh_ = *(const short8*)&PH[rb][nl][32 * (LC) + quad * 8];    \
    const short8 ul_ = *(const short8*)&PL[rb][nl][32 * (LC) + quad * 8];    \
    MTM(0, F0) MTM(1, F1) MTMS2(CI) MTMS3(CI)                                \
  }

// cell update for tile J; SINGLE h write into plane (PH,PL) at k = KO+cell
#define CUP(J, PH, PL, KO)                                                   \
  if (tv##J) {                                                               \
    const float I_ = rcpa(1.0f + fexp2(ac##J[0]));                           \
    const float F_ = rcpa(1.0f + fexp2(ac##J[1]));                           \
    const float G_ = fmaf(2.0f, rcpa(1.0f + fexp2(ac##J[2])), -1.0f);        \
    const float O_ = rcpa(1.0f + fexp2(ac##J[3]));                           \
    cs##J = fmaf(F_, cs##J, I_ * G_);                                        \
    const float tc_ = fmaf(2.0f, rcpa(1.0f + fexp2(cs##J * KS2f)), -1.0f);   \
    const float hv = O_ * tc_;                                               \
    hl##J = hv;                                                              \
    if (cell##J < Hn)                                                        \
      wsplit(&PH[wb][nl][(KO) + cell##J], &PL[wb][nl][(KO) + cell##J], hv);  \
  }

__global__ __launch_bounds__(768, 3) void lstm_fused(
    const float* __restrict__ xg,    // [B][T]
    const float* __restrict__ wih1, const float* __restrict__ whh1,
    const float* __restrict__ b1, const float* __restrict__ wih2,
    const float* __restrict__ whh2, const float* __restrict__ b2,
    const float* __restrict__ wih3, const float* __restrict__ whh3,
    const float* __restrict__ b3, const float* __restrict__ wfc,
    const float* __restrict__ bfc, float* __restrict__ out)  // [B]
{
  __shared__ __align__(16) short p1h[2][16][SW];  // [x | h1(1..50)]
  __shared__ __align__(16) short p1l[2][16][SW];
  __shared__ __align__(16) short p2h[2][16][SW];  // [h2(0..49)]
  __shared__ __align__(16) short p2l[2][16][SW];
  __shared__ __align__(16) short p3h[2][16][SW];  // [h3(0..49)]
  __shared__ __align__(16) short p3l[2][16][SW];
  __shared__ __align__(16) float s_bv[12][4][4][4];    // pre-scaled bias
  __shared__ __align__(16) short8 s_f4j2[2][4][4][2][64];  // J2 frags [L-1][wl][chunk][H/L][lane]
  __shared__ __align__(16) short8 s_f4j3[2][4][2][64];     // J3 (tile12) frags
  __shared__ float s_fc[4][16];

  const int tid = threadIdx.x;
  const int w = tid >> 6;
  const int lane = tid & 63;
  const int quad = lane >> 4;
  const int nl = lane & 15;
  const int L = (w < 4) ? 0 : (w < 8) ? 1 : 2;
  const int wl = w & 3;
  const int wz2 = (L == 2) ? 1 : 0;
  const int eb = blockIdx.x * 16;

  const float* wihL = (L == 0) ? wih1 : (L == 1) ? wih2 : wih3;
  const float* whhL = (L == 0) ? whh1 : (L == 1) ? whh2 : whh3;
  const float* biasL = (L == 0) ? b1 : (L == 1) ? b2 : b3;

  LW(0) LW(1) LW(2) LW(3) LW(4) LW(5) LW(6) LW(7)
  LW(8) LW(9) LW(10) LW(11)
  LW(16) LW(17) LW(18) LW(19)

  // park J2/J3 fragments in LDS; their registers die here
  if (L > 0) {
    s_f4j2[wz2][wl][0][0][lane] = FH8;  s_f4j2[wz2][wl][0][1][lane] = FL8;
    s_f4j2[wz2][wl][1][0][lane] = FH9;  s_f4j2[wz2][wl][1][1][lane] = FL9;
    s_f4j2[wz2][wl][2][0][lane] = FH10; s_f4j2[wz2][wl][2][1][lane] = FL10;
    s_f4j2[wz2][wl][3][0][lane] = FH11; s_f4j2[wz2][wl][3][1][lane] = FL11;
    if (wl == 0) {
      s_f4j3[wz2][0][0][lane] = FH16; s_f4j3[wz2][0][1][lane] = FL16;
      s_f4j3[wz2][1][0][lane] = FH17; s_f4j3[wz2][1][1][lane] = FL17;
      s_f4j3[wz2][2][0][lane] = FH18; s_f4j3[wz2][2][1][lane] = FL18;
      s_f4j3[wz2][3][0][lane] = FH19; s_f4j3[wz2][3][1][lane] = FL19;
    }
  }

  BINIT(0) BINIT(1) BINIT(2) BINIT(3)

  for (int i = tid; i < 2 * 16 * SW; i += 768) {
    (&p1h[0][0][0])[i] = 0;
    (&p1l[0][0][0])[i] = 0;
    (&p2h[0][0][0])[i] = 0;
    (&p2l[0][0][0])[i] = 0;
    (&p3h[0][0][0])[i] = 0;
    (&p3l[0][0][0])[i] = 0;
  }
  for (int i = tid; i < 12 * 4 * 4 * 4; i += 768) (&s_bv[0][0][0][0])[i] = 0.f;
  __syncthreads();
  if (w == 0 && lane < 16) {
    const float xv = xg[(size_t)(eb + lane) * Tn + 0];
    wsplit(&p1h[0][lane][0], &p1l[0][lane][0], xv);
  }
  if (nl == 0) {
    STB(0) STB(1) STB(2) STB(3)
  }
  __syncthreads();

#pragma unroll 1
  for (int i = 0; i < Tn + 2; ++i) {
    const int rb = i & 1, wb = rb ^ 1;
    if (L == 0) {
      if (i < Tn) {
        float xv = 0.f;
        if (w == 0 && lane < 16 && i + 1 < Tn)
          xv = xg[(size_t)(eb + lane) * Tn + (i + 1)];
        f32x4 ac0 = *(const f32x4*)s_bv[w][0][quad];
        f32x4 ac1 = *(const f32x4*)s_bv[w][1][quad];
        f32x4 ac2 = *(const f32x4*)s_bv[w][2][quad];
        f32x4 ac3 = *(const f32x4*)s_bv[w][3][quad];
        __builtin_amdgcn_s_setprio(1);   // T5: MFMA cluster
        MCH_L1(0, 0, 2, 4, 6)
        MCH_L1(1, 1, 3, 5, 7)
        __builtin_amdgcn_s_setprio(0);   // CUP / trans phase
        CUP(0, p1h, p1l, 1)
        CUP(1, p1h, p1l, 1)
        CUP(2, p1h, p1l, 1)
        CUP(3, p1h, p1l, 1)
        if (w == 0 && lane < 16)
          wsplit(&p1h[wb][lane][0], &p1l[wb][lane][0], xv);
      }
    } else if (L == 1) {
      if (i >= 1 && i <= Tn) {
        f32x4 ac0 = *(const f32x4*)s_bv[w][0][quad];
        f32x4 ac1 = *(const f32x4*)s_bv[w][1][quad];
        f32x4 ac2 = *(const f32x4*)s_bv[w][2][quad];
        f32x4 ac3 = *(const f32x4*)s_bv[w][3][quad];
        __builtin_amdgcn_s_setprio(1);   // T5: MFMA cluster
        MCH_L23(p1h, p1l, 0, 0, 0, 4)   // combined k 0..31  (h1)
        MCH_L23(p1h, p1l, 1, 1, 1, 5)   // combined k 32..63 (h1)
        MCH_L23(p2h, p2l, 0, 2, 2, 6)   // combined k 64..95 (h2)
        MCH_L23(p2h, p2l, 1, 3, 3, 7)   // combined k 96..127(h2)
        __builtin_amdgcn_s_setprio(0);   // CUP / trans phase
        CUP(0, p2h, p2l, 0)
        CUP(1, p2h, p2l, 0)
        CUP(2, p2h, p2l, 0)
        CUP(3, p2h, p2l, 0)
      }
    } else {
      if (i >= 2) {
        f32x4 ac0 = *(const f32x4*)s_bv[w][0][quad];
        f32x4 ac1 = *(const f32x4*)s_bv[w][1][quad];
        f32x4 ac2 = *(const f32x4*)s_bv[w][2][quad];
        f32x4 ac3 = *(const f32x4*)s_bv[w][3][quad];
        __builtin_amdgcn_s_setprio(1);   // T5: MFMA cluster
        MCH_L23(p2h, p2l, 0, 0, 0, 4)   // h2
        MCH_L23(p2h, p2l, 1, 1, 1, 5)
        MCH_L23(p3h, p3l, 0, 2, 2, 6)   // h3
        MCH_L23(p3h, p3l, 1, 3, 3, 7)
        __builtin_amdgcn_s_setprio(0);   // CUP / trans phase
        CUP(0, p3h, p3l, 0)
        CUP(1, p3h, p3l, 0)
        CUP(2, p3h, p3l, 0)
        CUP(3, p3h, p3l, 0)
      }
    }
    __syncthreads();
  }

  if (L == 2) {
    float pfc = 0.f;
    if (tv0 && cell0 < Hn) pfc += hl0 * wfc[cell0];
    if (tv1 && cell1 < Hn) pfc += hl1 * wfc[cell1];
    if (tv2 && cell2 < Hn) pfc += hl2 * wfc[cell2];
    if (tv3 && cell3 < Hn) pfc += hl3 * wfc[cell3];
    pfc += __shfl_xor(pfc, 16);  // sum over quads (cells)
    pfc += __shfl_xor(pfc, 32);
    if (lane < 16) s_fc[wl][lane] = pfc;
  }
  __syncthreads();
  if (tid < 16)
    out[eb + tid] = bfc[0] + s_fc[0][tid] + s_fc[1][tid] + s_fc[2][tid] +
                    s_fc[3][tid];
}

}  // namespace

extern "C" void kernel_launch(void* const* d_in, const int* in_sizes, int n_in,
                              void* d_out, int out_size, void* d_ws, size_t ws_size,
                              hipStream_t stream) {
  const float* x    = (const float*)d_in[0];
  const float* wih1 = (const float*)d_in[1];
  const float* whh1 = (const float*)d_in[2];
  const float* b1   = (const float*)d_in[3];
  const float* wih2 = (const float*)d_in[4];
  const float* whh2 = (const float*)d_in[5];
  const float* b2   = (const float*)d_in[6];
  const float* wih3 = (const float*)d_in[7];
  const float* whh3 = (const float*)d_in[8];
  const float* b3   = (const float*)d_in[9];
  const float* wfc  = (const float*)d_in[10];
  const float* bfc  = (const float*)d_in[11];
  float* out = (float*)d_out;

  lstm_fused<<<dim3(Bn / 16), dim3(768), 0, stream>>>(
      x, wih1, whh1, b1, wih2, whh2, b2, wih3, whh3, b3, wfc, bfc, out);
}